// Round 1
// baseline (884.545 us; speedup 1.0000x reference)
//
#include <hip/hip_runtime.h>
#include <math.h>

#define Bv 2
#define Lv 1024
#define Hv 16
#define Dv 64
#define HIDv 1024

// ---------------------------------------------------------------------------
// Generic tiled fp32 GEMM, C = alpha * A @ B
// A: MxK row-major, B: KxN row-major, C: MxN row-major.
// Batched over blockIdx.z with element strides sA,sB,sC.
// Requires M%64==0, N%64==0, K%16==0.
// ---------------------------------------------------------------------------
#define BM 64
#define BN 64
#define BK 16

__global__ __launch_bounds__(256) void gemm_nn(
    const float* __restrict__ A, const float* __restrict__ B,
    float* __restrict__ C, int M, int N, int K,
    long long sA, long long sB, long long sC, float alpha)
{
    __shared__ float As[BK][BM];
    __shared__ float Bs[BK][BN];
    A += (long long)blockIdx.z * sA;
    B += (long long)blockIdx.z * sB;
    C += (long long)blockIdx.z * sC;
    const int tx = threadIdx.x, ty = threadIdx.y;
    const int tid = ty * 16 + tx;
    const int m0 = blockIdx.y * BM;
    const int n0 = blockIdx.x * BN;
    float acc[4][4] = {};
    for (int k0 = 0; k0 < K; k0 += BK) {
        {   // A tile 64x16, float4 along k, transpose into As[kk][m]
            int e = tid * 4;
            int m = e >> 4;
            int kk = e & 15;
            const float4 av = *(const float4*)(A + (long long)(m0 + m) * K + k0 + kk);
            As[kk + 0][m] = av.x; As[kk + 1][m] = av.y;
            As[kk + 2][m] = av.z; As[kk + 3][m] = av.w;
        }
        {   // B tile 16x64, float4 along n
            int e = tid * 4;
            int kk = e >> 6;
            int n = e & 63;
            *(float4*)&Bs[kk][n] = *(const float4*)(B + (long long)(k0 + kk) * N + n0 + n);
        }
        __syncthreads();
        #pragma unroll
        for (int kk = 0; kk < BK; ++kk) {
            float4 a = *(const float4*)&As[kk][ty * 4];
            float4 b = *(const float4*)&Bs[kk][tx * 4];
            acc[0][0] += a.x * b.x; acc[0][1] += a.x * b.y; acc[0][2] += a.x * b.z; acc[0][3] += a.x * b.w;
            acc[1][0] += a.y * b.x; acc[1][1] += a.y * b.y; acc[1][2] += a.y * b.z; acc[1][3] += a.y * b.w;
            acc[2][0] += a.z * b.x; acc[2][1] += a.z * b.y; acc[2][2] += a.z * b.z; acc[2][3] += a.z * b.w;
            acc[3][0] += a.w * b.x; acc[3][1] += a.w * b.y; acc[3][2] += a.w * b.z; acc[3][3] += a.w * b.w;
        }
        __syncthreads();
    }
    #pragma unroll
    for (int i = 0; i < 4; ++i) {
        int m = m0 + ty * 4 + i;
        float4 v = make_float4(acc[i][0] * alpha, acc[i][1] * alpha,
                               acc[i][2] * alpha, acc[i][3] * alpha);
        *(float4*)(C + (long long)m * N + n0 + tx * 4) = v;
    }
}

// C = alpha * A @ B^T ; A: MxK, B: NxK (both row-major), C: MxN.
__global__ __launch_bounds__(256) void gemm_nt(
    const float* __restrict__ A, const float* __restrict__ B,
    float* __restrict__ C, int M, int N, int K,
    long long sA, long long sB, long long sC, float alpha)
{
    __shared__ float As[BK][BM];
    __shared__ float Bs[BK][BN];
    A += (long long)blockIdx.z * sA;
    B += (long long)blockIdx.z * sB;
    C += (long long)blockIdx.z * sC;
    const int tx = threadIdx.x, ty = threadIdx.y;
    const int tid = ty * 16 + tx;
    const int m0 = blockIdx.y * BM;
    const int n0 = blockIdx.x * BN;
    float acc[4][4] = {};
    for (int k0 = 0; k0 < K; k0 += BK) {
        {
            int e = tid * 4;
            int m = e >> 4;
            int kk = e & 15;
            const float4 av = *(const float4*)(A + (long long)(m0 + m) * K + k0 + kk);
            As[kk + 0][m] = av.x; As[kk + 1][m] = av.y;
            As[kk + 2][m] = av.z; As[kk + 3][m] = av.w;
        }
        {   // B^T tile: Bs[kk][n] = B[(n0+n)*K + k0+kk]
            int e = tid * 4;
            int n = e >> 4;
            int kk = e & 15;
            const float4 bv = *(const float4*)(B + (long long)(n0 + n) * K + k0 + kk);
            Bs[kk + 0][n] = bv.x; Bs[kk + 1][n] = bv.y;
            Bs[kk + 2][n] = bv.z; Bs[kk + 3][n] = bv.w;
        }
        __syncthreads();
        #pragma unroll
        for (int kk = 0; kk < BK; ++kk) {
            float4 a = *(const float4*)&As[kk][ty * 4];
            float4 b = *(const float4*)&Bs[kk][tx * 4];
            acc[0][0] += a.x * b.x; acc[0][1] += a.x * b.y; acc[0][2] += a.x * b.z; acc[0][3] += a.x * b.w;
            acc[1][0] += a.y * b.x; acc[1][1] += a.y * b.y; acc[1][2] += a.y * b.z; acc[1][3] += a.y * b.w;
            acc[2][0] += a.z * b.x; acc[2][1] += a.z * b.y; acc[2][2] += a.z * b.z; acc[2][3] += a.z * b.w;
            acc[3][0] += a.w * b.x; acc[3][1] += a.w * b.y; acc[3][2] += a.w * b.z; acc[3][3] += a.w * b.w;
        }
        __syncthreads();
    }
    #pragma unroll
    for (int i = 0; i < 4; ++i) {
        int m = m0 + ty * 4 + i;
        float4 v = make_float4(acc[i][0] * alpha, acc[i][1] * alpha,
                               acc[i][2] * alpha, acc[i][3] * alpha);
        *(float4*)(C + (long long)m * N + n0 + tx * 4) = v;
    }
}

// ---------------------------------------------------------------------------
// RoPE + split qkv(B,L,3,H,D) -> q,k,v in (B,H,L,D)
// ---------------------------------------------------------------------------
__global__ __launch_bounds__(256) void rope_split(
    const float* __restrict__ qkv,
    float* __restrict__ q, float* __restrict__ k, float* __restrict__ v)
{
    int idx = blockIdx.x * 256 + threadIdx.x;   // over B*H*L*D = 2M
    int d = idx & 63;
    int l = (idx >> 6) & 1023;
    int h = (idx >> 16) & 15;
    int b = idx >> 20;

    const long long src = ((long long)(b * Lv + l) * 3) * (Hv * Dv) + h * Dv + d;
    const long long dst = idx;  // (B,H,L,D) flat == idx by construction

    // rope tables: emb[l,d] = l * inv_freq[d % 32], inv_freq[i] = 10000^{-i/32}
    int i = d & 31;
    float inv_freq = __expf((float)i * -0.28782313662425574f); // -ln(10000)/32
    float arg = (float)l * inv_freq;
    float c, s;
    __sincosf(arg, &s, &c);

    // q
    {
        float x  = qkv[src];
        float xr = (d < 32) ? -qkv[src + 32] : qkv[src - 32];
        q[dst] = x * c + xr * s;
    }
    // k
    {
        float x  = qkv[src + Hv * Dv];
        float xr = (d < 32) ? -qkv[src + Hv * Dv + 32] : qkv[src + Hv * Dv - 32];
        k[dst] = x * c + xr * s;
    }
    // v (copy)
    v[dst] = qkv[src + 2 * Hv * Dv];
}

// ---------------------------------------------------------------------------
// Kerple + DAPE MLP, in-place on scores (B,H,L,L). Upper triangle -> -inf.
// grid: (L/256, L, B), block 256
// ---------------------------------------------------------------------------
__device__ __forceinline__ float gelu_exact(float x) {
    return 0.5f * x * (1.0f + erff(x * 0.70710678118654752f));
}

__global__ __launch_bounds__(256) void dape_mlp(
    float* __restrict__ scores,
    const float* __restrict__ log_p, const float* __restrict__ log_a,
    const float* __restrict__ w1, const float* __restrict__ b1,
    const float* __restrict__ w2, const float* __restrict__ b2)
{
    __shared__ float sw1[32 * 32];
    __shared__ float sw2[32 * 16];
    __shared__ float sb1[32];
    __shared__ float sb2[16];
    __shared__ float sp[16];
    __shared__ float sa[16];
    const int tid = threadIdx.x;
    for (int t = tid; t < 1024; t += 256) sw1[t] = w1[t];
    for (int t = tid; t < 512;  t += 256) sw2[t] = w2[t];
    if (tid < 32) sb1[tid] = b1[tid];
    if (tid < 16) {
        sb2[tid] = b2[tid];
        sp[tid] = log1pf(__expf(log_p[tid]));  // softplus
        sa[tid] = log1pf(__expf(log_a[tid]));
    }
    __syncthreads();

    const int j = blockIdx.x * 256 + tid;
    const int i = blockIdx.y;
    const int b = blockIdx.z;
    const long long LL = (long long)Lv * Lv;
    const long long bij = (long long)(b * Hv) * LL + (long long)i * Lv + j;

    if (j > i) {
        #pragma unroll
        for (int h = 0; h < 16; ++h) scores[bij + h * LL] = -INFINITY;
        return;
    }

    float sc[16];
    #pragma unroll
    for (int h = 0; h < 16; ++h) sc[h] = scores[bij + h * LL];

    const float dist = (float)(i - j);
    float comb[32];
    #pragma unroll
    for (int h = 0; h < 16; ++h) comb[h] = sc[h];
    #pragma unroll
    for (int h = 0; h < 16; ++h) comb[16 + h] = -sp[h] * log1pf(sa[h] * dist);

    float hid[32];
    #pragma unroll
    for (int o = 0; o < 32; ++o) {
        float acc = sb1[o];
        #pragma unroll
        for (int c = 0; c < 32; ++c) acc += comb[c] * sw1[c * 32 + o];
        hid[o] = gelu_exact(acc);
    }

    #pragma unroll
    for (int h = 0; h < 16; ++h) {
        float acc = sb2[h];
        #pragma unroll
        for (int o = 0; o < 32; ++o) acc += hid[o] * sw2[o * 16 + h];
        scores[bij + h * LL] = sc[h] + comb[16 + h] + acc;
    }
}

// ---------------------------------------------------------------------------
// Row softmax over last dim (1024). One block per row. In-place.
// ---------------------------------------------------------------------------
__global__ __launch_bounds__(256) void softmax_rows(float* __restrict__ scores)
{
    float* row = scores + (long long)blockIdx.x * Lv;
    const int t = threadIdx.x;
    __shared__ float red[256];

    float v0 = row[t], v1 = row[t + 256], v2 = row[t + 512], v3 = row[t + 768];
    float m = fmaxf(fmaxf(v0, v1), fmaxf(v2, v3));
    red[t] = m;
    __syncthreads();
    for (int off = 128; off > 0; off >>= 1) {
        if (t < off) red[t] = fmaxf(red[t], red[t + off]);
        __syncthreads();
    }
    m = red[0];
    __syncthreads();

    float e0 = __expf(v0 - m), e1 = __expf(v1 - m), e2 = __expf(v2 - m), e3 = __expf(v3 - m);
    red[t] = e0 + e1 + e2 + e3;
    __syncthreads();
    for (int off = 128; off > 0; off >>= 1) {
        if (t < off) red[t] += red[t + off];
        __syncthreads();
    }
    float inv = 1.0f / red[0];
    row[t] = e0 * inv; row[t + 256] = e1 * inv; row[t + 512] = e2 * inv; row[t + 768] = e3 * inv;
}

// ---------------------------------------------------------------------------
// (B,H,L,D) -> (B,L,H*D)
// ---------------------------------------------------------------------------
__global__ __launch_bounds__(256) void transpose_out(
    const float* __restrict__ src, float* __restrict__ dst)
{
    int idx = blockIdx.x * 256 + threadIdx.x;  // over output (B,L,H*D) = 2M
    int d = idx & 63;
    int h = (idx >> 6) & 15;
    int l = (idx >> 10) & 1023;
    int b = idx >> 20;
    dst[idx] = src[(((long long)(b * Hv + h)) * Lv + l) * Dv + d];
}

// ---------------------------------------------------------------------------
extern "C" void kernel_launch(void* const* d_in, const int* in_sizes, int n_in,
                              void* d_out, int out_size, void* d_ws, size_t ws_size,
                              hipStream_t stream)
{
    const float* x     = (const float*)d_in[0];   // (B,L,HID)
    const float* w_qkv = (const float*)d_in[1];   // (HID, 3*H*D)
    const float* w_o   = (const float*)d_in[2];   // (H*D, HID)
    const float* log_p = (const float*)d_in[3];   // (H,1,1)
    const float* log_a = (const float*)d_in[4];   // (H,1,1)
    const float* w1    = (const float*)d_in[5];   // (2H,2H)
    const float* b1    = (const float*)d_in[6];   // (2H,)
    const float* w2    = (const float*)d_in[7];   // (2H,H)
    const float* b2    = (const float*)d_in[8];   // (H,)
    float* out = (float*)d_out;                   // (B,L,HID)

    float* ws = (float*)d_ws;
    const long long nBHLD = (long long)Bv * Hv * Lv * Dv;      // 2,097,152
    const long long nQKV  = (long long)Bv * Lv * 3 * Hv * Dv;  // 6,291,456
    const long long LL    = (long long)Lv * Lv;

    float* qkv      = ws;                       // 6.29M floats
    float* q        = ws + nQKV;                // 2.10M
    float* k        = q + nBHLD;
    float* v        = k + nBHLD;
    float* scores   = v + nBHLD;                // 33.55M floats (B,H,L,L)
    float* attn_tmp = ws;                       // reuse qkv region (B,H,L,D)
    float* attn_fl  = ws + nBHLD;               // (B,L,H*D)

    dim3 blk(16, 16);

    // 1. qkv = x @ w_qkv   (2048 x 3072 x K=1024)
    gemm_nn<<<dim3(3 * Hv * Dv / BN, Bv * Lv / BM, 1), blk, 0, stream>>>(
        x, w_qkv, qkv, Bv * Lv, 3 * Hv * Dv, HIDv, 0, 0, 0, 1.0f);

    // 2. rope + split
    rope_split<<<(int)(nBHLD / 256), 256, 0, stream>>>(qkv, q, k, v);

    // 3. scores = (q @ k^T) * 1/sqrt(D), batched over B*H
    gemm_nt<<<dim3(Lv / BN, Lv / BM, Bv * Hv), blk, 0, stream>>>(
        q, k, scores, Lv, Lv, Dv,
        (long long)Lv * Dv, (long long)Lv * Dv, LL, 0.125f);

    // 4. kerple + DAPE MLP + causal mask, in-place
    dape_mlp<<<dim3(Lv / 256, Lv, Bv), 256, 0, stream>>>(
        scores, log_p, log_a, w1, b1, w2, b2);

    // 5. softmax rows
    softmax_rows<<<Bv * Hv * Lv, 256, 0, stream>>>(scores);

    // 6. attn_tmp = weights @ v, batched over B*H  (1024 x 64 x K=1024)
    gemm_nn<<<dim3(Dv / BN, Lv / BM, Bv * Hv), blk, 0, stream>>>(
        scores, v, attn_tmp, Lv, Dv, Lv,
        LL, (long long)Lv * Dv, (long long)Lv * Dv, 1.0f);

    // 7. (B,H,L,D) -> (B,L,H*D)
    transpose_out<<<(int)(nBHLD / 256), 256, 0, stream>>>(attn_tmp, attn_fl);

    // 8. out = attn_fl @ w_o  (2048 x 1024 x K=1024)
    gemm_nn<<<dim3(HIDv / BN, Bv * Lv / BM, 1), blk, 0, stream>>>(
        attn_fl, w_o, out, Bv * Lv, HIDv, Hv * Dv, 0, 0, 0, 1.0f);
}